// Round 3
// baseline (140.264 us; speedup 1.0000x reference)
//
#include <hip/hip_runtime.h>

#define SEQ 8192
#define DIM 2048
#define NEG 0.02f

// ---------------------------------------------------------------------------
// K0: repack w1 [16][2048][3] -> wT [2048][16][4] (k-padded float4) so that
// one wave's per-cin weights (4 channels x 4) are a single aligned 64B
// scalar load (s_load_dwordx16).
// ---------------------------------------------------------------------------
__global__ __launch_bounds__(256) void k_prep(
    const float* __restrict__ w1, float* __restrict__ wT) {
  int i = blockIdx.x * 256 + threadIdx.x;   // i = cin*16 + c
  if (i < 32768) {
    int cin = i >> 4, c = i & 15;
    const float* s = w1 + c * 6144 + cin * 3;
    ((float4*)wT)[i] = make_float4(s[0], s[1], s[2], 0.f);
  }
}

// ---------------------------------------------------------------------------
// K1: conv1 partials. grid 512 = 32 t-blocks x 16 cin-slices, block 256.
// Wave wv owns channels 4*wv..4*wv+3 (weights are wave-uniform -> SGPRs via
// scalar loads; zero LDS traffic for weights). Lane owns t = t0+4*lane+tt.
// x staged transposed in LDS, skewed rows for conflict-free writes.
// Per cin per wave: 48 FMA (96 VALU cyc) vs ~12 LDS cyc  -> VALU-bound.
// ---------------------------------------------------------------------------
__device__ __forceinline__ int row_off(int j) {  // skewed row offset (words)
  return j * 260 + (j >> 2) * 4;                 // quad stride 1044 (bank+20)
}

__global__ __launch_bounds__(256, 2) void k_conv1(
    const float* __restrict__ x, const float* __restrict__ wT,
    float* __restrict__ out1p) {
  __shared__ float xs[8348];   // 32 skewed rows x 260 (+ quad skew) = 33.4KB

  const int tid = threadIdx.x;
  const int tb = blockIdx.x & 31;         // t0 = tb*256
  const int slice = blockIdx.x >> 5;      // cin slice of 128
  const int cinb = slice << 7;
  const int lane = tid & 63;
  const int wv = __builtin_amdgcn_readfirstlane(tid >> 6);  // uniform 0..3
  const int t0 = tb << 8;
  const int qc = tid & 7;                 // staging cin-quad
  const int rs = tid >> 3;                // staging row group (0..31)
  const float4* x4 = (const float4*)x;

  float acc[4][4];
  #pragma unroll
  for (int i = 0; i < 4; ++i)
    #pragma unroll
    for (int tt = 0; tt < 4; ++tt) acc[i][tt] = 0.f;

  const float* xrow = xs + (lane << 2);

  for (int ch = 0; ch < 4; ++ch) {
    __syncthreads();
    // stage 32 cin x 258 rows (gt = t0-1+r), transposed + skewed
    #pragma unroll
    for (int it = 0; it < 9; ++it) {
      int r = rs + (it << 5);
      if (r < 258) {
        int gt = t0 - 1 + r;
        float4 v = make_float4(0.f, 0.f, 0.f, 0.f);
        if (gt >= 0 && gt < SEQ)
          v = x4[gt * 512 + (cinb >> 2) + (ch << 3) + qc];
        xs[row_off(4 * qc + 0) + r] = v.x;
        xs[row_off(4 * qc + 1) + r] = v.y;
        xs[row_off(4 * qc + 2) + r] = v.z;
        xs[row_off(4 * qc + 3) + r] = v.w;
      }
    }
    __syncthreads();

    // weights for this chunk: wT[(cinb+ch*32+cin)*16 + wv*4 + i]
    const float4* wq = ((const float4*)wT) + (((cinb + (ch << 5)) << 4) + (wv << 2));

    #pragma unroll 8
    for (int cin = 0; cin < 32; ++cin) {
      float4 w0 = wq[(cin << 4) + 0];
      float4 w1v = wq[(cin << 4) + 1];
      float4 w2v = wq[(cin << 4) + 2];
      float4 w3v = wq[(cin << 4) + 3];
      const float* xb = xrow + row_off(cin);
      float4 xa = *(const float4*)xb;
      float2 xt = *(const float2*)(xb + 4);
      float xv[6] = {xa.x, xa.y, xa.z, xa.w, xt.x, xt.y};
      #pragma unroll
      for (int tt = 0; tt < 4; ++tt) {
        acc[0][tt] += w0.x * xv[tt] + w0.y * xv[tt + 1] + w0.z * xv[tt + 2];
        acc[1][tt] += w1v.x * xv[tt] + w1v.y * xv[tt + 1] + w1v.z * xv[tt + 2];
        acc[2][tt] += w2v.x * xv[tt] + w2v.y * xv[tt + 1] + w2v.z * xv[tt + 2];
        acc[3][tt] += w3v.x * xv[tt] + w3v.y * xv[tt + 1] + w3v.z * xv[tt + 2];
      }
    }
  }

  #pragma unroll
  for (int i = 0; i < 4; ++i) {
    float4 o = make_float4(acc[i][0], acc[i][1], acc[i][2], acc[i][3]);
    int c = (wv << 2) + i;
    ((float4*)out1p)[(slice * 16 + c) * 2048 + (t0 >> 2) + lane] = o;
  }
}

// ---------------------------------------------------------------------------
// K2: sum conv1 partials + bias + leaky, then conv2..conv5 fused.
// grid 128, block 128, T=64 per block. j in 0..71 <-> t = t0-4+j.
// ---------------------------------------------------------------------------
__global__ __launch_bounds__(128) void k_chain(
    const float* __restrict__ out1p, const float* __restrict__ b1,
    const float* __restrict__ w2, const float* __restrict__ b2,
    const float* __restrict__ w3, const float* __restrict__ b3,
    const float* __restrict__ w4, const float* __restrict__ b4,
    const float* __restrict__ w5, const float* __restrict__ b5,
    float* __restrict__ y5) {
  __shared__ float l1[16][72], l2[8][72], l3[4][72], l4[2][72];
  __shared__ float w2s[384], w3s[96], w4s[24], w5s[6];
  __shared__ float bs[16];

  const int tid = threadIdx.x;
  const int t0 = blockIdx.x * 64;

  for (int i = tid; i < 384; i += 128) w2s[i] = w2[i];
  if (tid < 96) w3s[tid] = w3[tid];
  else if (tid < 120) w4s[tid - 96] = w4[tid - 96];
  else if (tid == 120) { for (int i = 0; i < 6; ++i) w5s[i] = w5[i]; }
  else if (tid == 121) {
    for (int i = 0; i < 8; ++i) bs[i] = b2[i];
    for (int i = 0; i < 4; ++i) bs[8 + i] = b3[i];
    bs[12] = b4[0]; bs[13] = b4[1]; bs[14] = b5[0];
  }

  const float4* p4 = (const float4*)out1p;
  for (int idx = tid; idx < 16 * 18; idx += 128) {
    int cc = idx / 18, m = idx - cc * 18;
    int gt0 = t0 - 4 + 4 * m;
    float4 a = make_float4(0.f, 0.f, 0.f, 0.f);
    if (gt0 >= 0 && gt0 < SEQ) {
      int base = cc * 2048 + (gt0 >> 2);
      #pragma unroll
      for (int s = 0; s < 16; ++s) {
        float4 v = p4[s * 16 * 2048 + base];
        a.x += v.x; a.y += v.y; a.z += v.z; a.w += v.w;
      }
    }
    float bb = b1[cc];
    float e0 = a.x + bb, e1 = a.y + bb, e2 = a.z + bb, e3 = a.w + bb;
    l1[cc][4 * m + 0] = (e0 >= 0.f) ? e0 : NEG * e0;
    l1[cc][4 * m + 1] = (e1 >= 0.f) ? e1 : NEG * e1;
    l1[cc][4 * m + 2] = (e2 >= 0.f) ? e2 : NEG * e2;
    l1[cc][4 * m + 3] = (e3 >= 0.f) ? e3 : NEG * e3;
  }
  __syncthreads();

  for (int o = tid; o < 560; o += 128) {
    int j = (o >> 3) + 1, cc = o & 7;
    float acc = bs[cc];
    #pragma unroll
    for (int ci = 0; ci < 16; ++ci) {
      acc += w2s[cc * 48 + ci * 3 + 0] * l1[ci][j - 1];
      acc += w2s[cc * 48 + ci * 3 + 1] * l1[ci][j];
      acc += w2s[cc * 48 + ci * 3 + 2] * l1[ci][j + 1];
    }
    l2[cc][j] = (acc >= 0.f) ? acc : NEG * acc;
  }
  __syncthreads();

  for (int o = tid; o < 272; o += 128) {
    int j = (o >> 2) + 2, cc = o & 3;
    float acc = bs[8 + cc];
    #pragma unroll
    for (int ci = 0; ci < 8; ++ci) {
      acc += w3s[cc * 24 + ci * 3 + 0] * l2[ci][j - 1];
      acc += w3s[cc * 24 + ci * 3 + 1] * l2[ci][j];
      acc += w3s[cc * 24 + ci * 3 + 2] * l2[ci][j + 1];
    }
    l3[cc][j] = (acc >= 0.f) ? acc : NEG * acc;
  }
  __syncthreads();

  for (int o = tid; o < 132; o += 128) {
    int j = (o >> 1) + 3, cc = o & 1;
    float acc = bs[12 + cc];
    #pragma unroll
    for (int ci = 0; ci < 4; ++ci) {
      acc += w4s[cc * 12 + ci * 3 + 0] * l3[ci][j - 1];
      acc += w4s[cc * 12 + ci * 3 + 1] * l3[ci][j];
      acc += w4s[cc * 12 + ci * 3 + 2] * l3[ci][j + 1];
    }
    l4[cc][j] = (acc >= 0.f) ? acc : NEG * acc;
  }
  __syncthreads();

  for (int o = tid; o < 64; o += 128) {
    int j = o + 4;
    float acc = bs[14];
    #pragma unroll
    for (int ci = 0; ci < 2; ++ci) {
      acc += w5s[ci * 3 + 0] * l4[ci][j - 1];
      acc += w5s[ci * 3 + 1] * l4[ci][j];
      acc += w5s[ci * 3 + 2] * l4[ci][j + 1];
    }
    y5[t0 + o] = (acc >= 0.f) ? acc : NEG * acc;
  }
}

// ---------------------------------------------------------------------------
// K3: logits = Wl @ y5 + bl. grid 1024 (8 rows/block), block 256.
// ---------------------------------------------------------------------------
__global__ __launch_bounds__(256) void k_matvec(
    const float* __restrict__ Wl, const float* __restrict__ bl,
    const float* __restrict__ y5, float* __restrict__ logits) {
  const int tid = threadIdx.x;
  const int r0 = blockIdx.x * 8;
  const float4* W4 = (const float4*)Wl;
  const float4* y4 = (const float4*)y5;

  float a[8];
  #pragma unroll
  for (int r = 0; r < 8; ++r) a[r] = 0.f;

  #pragma unroll 2
  for (int u = 0; u < 8; ++u) {
    int i = u * 256 + tid;
    float4 yv = y4[i];
    #pragma unroll
    for (int r = 0; r < 8; ++r) {
      float4 wv = W4[(r0 + r) * 2048 + i];
      a[r] += wv.x * yv.x + wv.y * yv.y + wv.z * yv.z + wv.w * yv.w;
    }
  }
  #pragma unroll
  for (int o = 32; o; o >>= 1) {
    #pragma unroll
    for (int r = 0; r < 8; ++r) a[r] += __shfl_down(a[r], o);
  }
  __shared__ float red[4][8];
  const int lane = tid & 63, wid = tid >> 6;
  if (lane == 0) {
    #pragma unroll
    for (int r = 0; r < 8; ++r) red[wid][r] = a[r];
  }
  __syncthreads();
  if (tid < 8) {
    float s = red[0][tid] + red[1][tid] + red[2][tid] + red[3][tid];
    logits[r0 + tid] = s + bl[r0 + tid];
  }
}

// ---------------------------------------------------------------------------
// K3.5: softmax stats -> stats[0]=M, stats[1]=1/S. grid 1.
// ---------------------------------------------------------------------------
__global__ __launch_bounds__(256) void k_stats(
    const float* __restrict__ logits, float* __restrict__ stats) {
  __shared__ float red[4];
  const int tid = threadIdx.x;
  const int lane = tid & 63, wid = tid >> 6;

  float lv[32];
  #pragma unroll
  for (int i = 0; i < 32; ++i) lv[i] = logits[tid + 256 * i];

  float m = lv[0];
  #pragma unroll
  for (int i = 1; i < 32; ++i) m = fmaxf(m, lv[i]);
  #pragma unroll
  for (int o = 32; o; o >>= 1) m = fmaxf(m, __shfl_down(m, o));
  if (lane == 0) red[wid] = m;
  __syncthreads();
  const float M = fmaxf(fmaxf(red[0], red[1]), fmaxf(red[2], red[3]));
  __syncthreads();

  float s = 0.f;
  #pragma unroll
  for (int i = 0; i < 32; ++i) s += __expf(lv[i] - M);
  #pragma unroll
  for (int o = 32; o; o >>= 1) s += __shfl_down(s, o);
  if (lane == 0) red[wid] = s;
  __syncthreads();
  if (tid == 0) {
    float S = red[0] + red[1] + red[2] + red[3];
    stats[0] = M;
    stats[1] = 1.0f / S;
  }
}

// ---------------------------------------------------------------------------
// K4: weighted-sum partials. grid 1024 = 128 tc x 8 strips, block 256.
// ---------------------------------------------------------------------------
__global__ __launch_bounds__(256) void k_wsum(
    const float* __restrict__ x, const float* __restrict__ logits,
    const float* __restrict__ stats, float* __restrict__ partial) {
  const int tid = threadIdx.x;
  const int lane = tid & 63, wv = tid >> 6;
  const int tc = blockIdx.x >> 3, strip = blockIdx.x & 7;
  const float M = stats[0], invS = stats[1];
  const float4* x4 = (const float4*)x;
  const int col = strip * 64 + lane;
  const int t0 = tc * 64 + wv * 16;

  float4 acc = make_float4(0.f, 0.f, 0.f, 0.f);
  #pragma unroll 4
  for (int tt = 0; tt < 16; ++tt) {
    int t = t0 + tt;
    float a = __expf(logits[t] - M) * invS;
    float4 xv = x4[t * 512 + col];
    acc.x += a * xv.x; acc.y += a * xv.y; acc.z += a * xv.z; acc.w += a * xv.w;
  }

  __shared__ float4 redx[4][64];
  redx[wv][lane] = acc;
  __syncthreads();
  if (wv == 0) {
    float4 s = redx[0][lane];
    #pragma unroll
    for (int w = 1; w < 4; ++w) {
      float4 v = redx[w][lane];
      s.x += v.x; s.y += v.y; s.z += v.z; s.w += v.w;
    }
    ((float4*)partial)[tc * 512 + col] = s;
  }
}

// ---------------------------------------------------------------------------
// K5: out[d] = sum_{tc<128} partial[tc][d]. grid 8, block 256.
// ---------------------------------------------------------------------------
__global__ __launch_bounds__(256) void k_reduce(
    const float* __restrict__ partial, float* __restrict__ out) {
  const int col = blockIdx.x * 256 + threadIdx.x;
  float s = 0.f;
  #pragma unroll 8
  for (int tc = 0; tc < 128; ++tc) s += partial[tc * 2048 + col];
  out[col] = s;
}

// ---------------------------------------------------------------------------
extern "C" void kernel_launch(void* const* d_in, const int* in_sizes, int n_in,
                              void* d_out, int out_size, void* d_ws, size_t ws_size,
                              hipStream_t stream) {
  const float* x  = (const float*)d_in[0];
  const float* w1 = (const float*)d_in[1];
  const float* b1 = (const float*)d_in[2];
  const float* w2 = (const float*)d_in[3];
  const float* b2 = (const float*)d_in[4];
  const float* w3 = (const float*)d_in[5];
  const float* b3 = (const float*)d_in[6];
  const float* w4 = (const float*)d_in[7];
  const float* b4 = (const float*)d_in[8];
  const float* w5 = (const float*)d_in[9];
  const float* b5 = (const float*)d_in[10];
  const float* Wl = (const float*)d_in[11];
  const float* bl = (const float*)d_in[12];
  float* out = (float*)d_out;

  float* ws      = (float*)d_ws;
  float* wT      = ws;                        // 2048*16*4 = 131072
  float* out1p   = wT + 131072;               // 16*16*8192 = 2097152
  float* y5      = out1p + 16 * 16 * SEQ;     // 8192
  float* logits  = y5 + SEQ;                  // 8192
  float* stats   = logits + SEQ;              // 16
  float* partial = stats + 16;                // 128*2048

  k_prep  <<<128, 256, 0, stream>>>(w1, wT);
  k_conv1 <<<512, 256, 0, stream>>>(x, wT, out1p);
  k_chain <<<128, 128, 0, stream>>>(out1p, b1, w2, b2, w3, b3, w4, b4, w5, b5, y5);
  k_matvec<<<1024, 256, 0, stream>>>(Wl, bl, y5, logits);
  k_stats <<<1, 256, 0, stream>>>(logits, stats);
  k_wsum  <<<1024, 256, 0, stream>>>(x, logits, stats, partial);
  k_reduce<<<8, 256, 0, stream>>>(partial, out);
}

// Round 4
// 136.670 us; speedup vs baseline: 1.0263x; 1.0263x over previous
//
#include <hip/hip_runtime.h>

#define SEQ 8192
#define DIM 2048
#define NEG 0.02f

// ---------------------------------------------------------------------------
// K1: conv1 partials. grid 512 = 16 t-blocks x 32 cin-slices, block 256.
// Wave wv owns channels 4wv..4wv+3; weights read from LDS at WAVE-UNIFORM
// addresses (broadcast, conflict-free). Lane owns 8 t = two 4t tiles
// (t0+4*lane+tt, t0+256+4*lane+tt). x staged transposed+skewed in LDS,
// 16-cin chunks. Per 4-cin group per wave: 12 uniform b128 (w) +
// 4 rows x 2 tiles x (b128+b64) (x) = ~216 LDS cyc vs 768 VALU cyc.
// ---------------------------------------------------------------------------
__device__ __forceinline__ int row_off(int j) {   // skewed row base (words)
  return j * 520 + (j >> 2) * 4;  // row = [258 tile0][pad2][258 tile1][pad2]
}

__global__ __launch_bounds__(256, 2) void k_conv1(
    const float* __restrict__ x, const float* __restrict__ w1,
    float* __restrict__ out1p) {
  __shared__ float wlds[16 * 16 * 12];  // [group g][c][k*4+u]  12.3KB
  __shared__ float xs[8332];            // 16 rows x 520 + skew  33.3KB

  const int tid = threadIdx.x;
  const int tb = blockIdx.x & 15;       // t0 = tb*512
  const int slice = blockIdx.x >> 4;    // 32 slices x 64 cin
  const int cinb = slice << 6;
  const int lane = tid & 63;
  const int wv = __builtin_amdgcn_readfirstlane(tid >> 6);  // 0..3
  const int t0 = tb << 9;
  const float4* x4 = (const float4*)x;

  // stage weights for whole slice: w1[c][cinb+4g+u][k] -> wlds[g][c][k*4+u]
  for (int i = tid; i < 3072; i += 256) {
    int g = i / 192;
    int rem = i - g * 192;
    int c = rem / 12;
    int m = rem - c * 12;
    int k = m >> 2, u = m & 3;
    wlds[i] = w1[c * 6144 + (cinb + 4 * g + u) * 3 + k];
  }

  float acc[4][8];
  #pragma unroll
  for (int i = 0; i < 4; ++i)
    #pragma unroll
    for (int t = 0; t < 8; ++t) acc[i][t] = 0.f;

  const int qc = tid & 3;               // staging cin-quad (chunk-local)
  const int rsb = tid >> 2;             // staging row 0..63

  for (int ch = 0; ch < 4; ++ch) {      // 4 chunks of 16 cin
    __syncthreads();
    // stage 16 cin x (258+258) t values, transposed + skewed
    #pragma unroll
    for (int it = 0; it < 9; ++it) {
      int srr = rsb + (it << 6);
      if (srr < 516) {
        int region = (srr >= 258) ? 1 : 0;
        int rr = srr - 258 * region;
        int gt = t0 - 1 + rr + (region << 8);
        float4 v = make_float4(0.f, 0.f, 0.f, 0.f);
        if (gt >= 0 && gt < SEQ)
          v = x4[gt * 512 + (cinb >> 2) + (ch << 2) + qc];
        int base = region * 260 + rr;
        xs[row_off(4 * qc + 0) + base] = v.x;
        xs[row_off(4 * qc + 1) + base] = v.y;
        xs[row_off(4 * qc + 2) + base] = v.z;
        xs[row_off(4 * qc + 3) + base] = v.w;
      }
    }
    __syncthreads();

    #pragma unroll 2
    for (int gg = 0; gg < 4; ++gg) {    // 4-cin groups in chunk
      const float4* wq = ((const float4*)wlds) +
                         ((((ch << 2) + gg) * 16 + (wv << 2)) * 3);
      float4 wk[12];                    // 4 ch x 3 float4 (wave-uniform addr)
      #pragma unroll
      for (int m = 0; m < 12; ++m) wk[m] = wq[m];
      const float* wkf = (const float*)wk;  // [(i*3+k)*4+u]

      #pragma unroll
      for (int u = 0; u < 4; ++u) {
        const float* xb = xs + row_off((gg << 2) + u) + (lane << 2);
        #pragma unroll
        for (int T = 0; T < 2; ++T) {
          float4 xa = *(const float4*)(xb + 260 * T);
          float2 xt = *(const float2*)(xb + 260 * T + 4);
          float xv[6] = {xa.x, xa.y, xa.z, xa.w, xt.x, xt.y};
          #pragma unroll
          for (int i = 0; i < 4; ++i) {
            float w0 = wkf[(i * 3 + 0) * 4 + u];
            float w1v = wkf[(i * 3 + 1) * 4 + u];
            float w2v = wkf[(i * 3 + 2) * 4 + u];
            #pragma unroll
            for (int tt = 0; tt < 4; ++tt)
              acc[i][T * 4 + tt] +=
                  w0 * xv[tt] + w1v * xv[tt + 1] + w2v * xv[tt + 2];
          }
        }
      }
    }
  }

  #pragma unroll
  for (int i = 0; i < 4; ++i) {
    int c = (wv << 2) + i;
    float4 o0 = make_float4(acc[i][0], acc[i][1], acc[i][2], acc[i][3]);
    float4 o1 = make_float4(acc[i][4], acc[i][5], acc[i][6], acc[i][7]);
    float4* dst = ((float4*)out1p) + (slice * 16 + c) * 2048 + (t0 >> 2);
    dst[lane] = o0;
    dst[64 + lane] = o1;
  }
}

// ---------------------------------------------------------------------------
// K2: sum 32 conv1 partials + bias + leaky, then conv2..conv5 fused.
// grid 128, block 128, T=64 per block. j in 0..71 <-> t = t0-4+j.
// ---------------------------------------------------------------------------
__global__ __launch_bounds__(128) void k_chain(
    const float* __restrict__ out1p, const float* __restrict__ b1,
    const float* __restrict__ w2, const float* __restrict__ b2,
    const float* __restrict__ w3, const float* __restrict__ b3,
    const float* __restrict__ w4, const float* __restrict__ b4,
    const float* __restrict__ w5, const float* __restrict__ b5,
    float* __restrict__ y5) {
  __shared__ float l1[16][72], l2[8][72], l3[4][72], l4[2][72];
  __shared__ float w2s[384], w3s[96], w4s[24], w5s[6];
  __shared__ float bs[16];

  const int tid = threadIdx.x;
  const int t0 = blockIdx.x * 64;

  for (int i = tid; i < 384; i += 128) w2s[i] = w2[i];
  if (tid < 96) w3s[tid] = w3[tid];
  else if (tid < 120) w4s[tid - 96] = w4[tid - 96];
  else if (tid == 120) { for (int i = 0; i < 6; ++i) w5s[i] = w5[i]; }
  else if (tid == 121) {
    for (int i = 0; i < 8; ++i) bs[i] = b2[i];
    for (int i = 0; i < 4; ++i) bs[8 + i] = b3[i];
    bs[12] = b4[0]; bs[13] = b4[1]; bs[14] = b5[0];
  }

  const float4* p4 = (const float4*)out1p;
  for (int idx = tid; idx < 16 * 18; idx += 128) {
    int cc = idx / 18, m = idx - cc * 18;
    int gt0 = t0 - 4 + 4 * m;
    if (gt0 >= 0 && gt0 < SEQ) {
      float4 a = make_float4(0.f, 0.f, 0.f, 0.f);
      int base = cc * 2048 + (gt0 >> 2);
      #pragma unroll 8
      for (int s = 0; s < 32; ++s) {
        float4 v = p4[s * 16 * 2048 + base];
        a.x += v.x; a.y += v.y; a.z += v.z; a.w += v.w;
      }
      float bb = b1[cc];
      float e0 = a.x + bb, e1 = a.y + bb, e2 = a.z + bb, e3 = a.w + bb;
      l1[cc][4 * m + 0] = (e0 >= 0.f) ? e0 : NEG * e0;
      l1[cc][4 * m + 1] = (e1 >= 0.f) ? e1 : NEG * e1;
      l1[cc][4 * m + 2] = (e2 >= 0.f) ? e2 : NEG * e2;
      l1[cc][4 * m + 3] = (e3 >= 0.f) ? e3 : NEG * e3;
    } else {
      l1[cc][4 * m + 0] = 0.f; l1[cc][4 * m + 1] = 0.f;
      l1[cc][4 * m + 2] = 0.f; l1[cc][4 * m + 3] = 0.f;
    }
  }
  __syncthreads();

  for (int o = tid; o < 560; o += 128) {
    int j = (o >> 3) + 1, cc = o & 7;
    float acc = bs[cc];
    #pragma unroll
    for (int ci = 0; ci < 16; ++ci) {
      acc += w2s[cc * 48 + ci * 3 + 0] * l1[ci][j - 1];
      acc += w2s[cc * 48 + ci * 3 + 1] * l1[ci][j];
      acc += w2s[cc * 48 + ci * 3 + 2] * l1[ci][j + 1];
    }
    l2[cc][j] = (acc >= 0.f) ? acc : NEG * acc;
  }
  __syncthreads();

  for (int o = tid; o < 272; o += 128) {
    int j = (o >> 2) + 2, cc = o & 3;
    float acc = bs[8 + cc];
    #pragma unroll
    for (int ci = 0; ci < 8; ++ci) {
      acc += w3s[cc * 24 + ci * 3 + 0] * l2[ci][j - 1];
      acc += w3s[cc * 24 + ci * 3 + 1] * l2[ci][j];
      acc += w3s[cc * 24 + ci * 3 + 2] * l2[ci][j + 1];
    }
    l3[cc][j] = (acc >= 0.f) ? acc : NEG * acc;
  }
  __syncthreads();

  for (int o = tid; o < 132; o += 128) {
    int j = (o >> 1) + 3, cc = o & 1;
    float acc = bs[12 + cc];
    #pragma unroll
    for (int ci = 0; ci < 4; ++ci) {
      acc += w4s[cc * 12 + ci * 3 + 0] * l3[ci][j - 1];
      acc += w4s[cc * 12 + ci * 3 + 1] * l3[ci][j];
      acc += w4s[cc * 12 + ci * 3 + 2] * l3[ci][j + 1];
    }
    l4[cc][j] = (acc >= 0.f) ? acc : NEG * acc;
  }
  __syncthreads();

  for (int o = tid; o < 64; o += 128) {
    int j = o + 4;
    float acc = bs[14];
    #pragma unroll
    for (int ci = 0; ci < 2; ++ci) {
      acc += w5s[ci * 3 + 0] * l4[ci][j - 1];
      acc += w5s[ci * 3 + 1] * l4[ci][j];
      acc += w5s[ci * 3 + 2] * l4[ci][j + 1];
    }
    y5[t0 + o] = (acc >= 0.f) ? acc : NEG * acc;
  }
}

// ---------------------------------------------------------------------------
// K3: logits = Wl @ y5 + bl. grid 1024 (8 rows/block), block 256.
// ---------------------------------------------------------------------------
__global__ __launch_bounds__(256) void k_matvec(
    const float* __restrict__ Wl, const float* __restrict__ bl,
    const float* __restrict__ y5, float* __restrict__ logits) {
  const int tid = threadIdx.x;
  const int r0 = blockIdx.x * 8;
  const float4* W4 = (const float4*)Wl;
  const float4* y4 = (const float4*)y5;

  float a[8];
  #pragma unroll
  for (int r = 0; r < 8; ++r) a[r] = 0.f;

  #pragma unroll 2
  for (int u = 0; u < 8; ++u) {
    int i = u * 256 + tid;
    float4 yv = y4[i];
    #pragma unroll
    for (int r = 0; r < 8; ++r) {
      float4 wv = W4[(r0 + r) * 2048 + i];
      a[r] += wv.x * yv.x + wv.y * yv.y + wv.z * yv.z + wv.w * yv.w;
    }
  }
  #pragma unroll
  for (int o = 32; o; o >>= 1) {
    #pragma unroll
    for (int r = 0; r < 8; ++r) a[r] += __shfl_down(a[r], o);
  }
  __shared__ float red[4][8];
  const int lane = tid & 63, wid = tid >> 6;
  if (lane == 0) {
    #pragma unroll
    for (int r = 0; r < 8; ++r) red[wid][r] = a[r];
  }
  __syncthreads();
  if (tid < 8) {
    float s = red[0][tid] + red[1][tid] + red[2][tid] + red[3][tid];
    logits[r0 + tid] = s + bl[r0 + tid];
  }
}

// ---------------------------------------------------------------------------
// K3.5: softmax stats -> stats[0]=M, stats[1]=1/S. grid 1.
// ---------------------------------------------------------------------------
__global__ __launch_bounds__(256) void k_stats(
    const float* __restrict__ logits, float* __restrict__ stats) {
  __shared__ float red[4];
  const int tid = threadIdx.x;
  const int lane = tid & 63, wid = tid >> 6;

  float lv[32];
  #pragma unroll
  for (int i = 0; i < 32; ++i) lv[i] = logits[tid + 256 * i];

  float m = lv[0];
  #pragma unroll
  for (int i = 1; i < 32; ++i) m = fmaxf(m, lv[i]);
  #pragma unroll
  for (int o = 32; o; o >>= 1) m = fmaxf(m, __shfl_down(m, o));
  if (lane == 0) red[wid] = m;
  __syncthreads();
  const float M = fmaxf(fmaxf(red[0], red[1]), fmaxf(red[2], red[3]));
  __syncthreads();

  float s = 0.f;
  #pragma unroll
  for (int i = 0; i < 32; ++i) s += __expf(lv[i] - M);
  #pragma unroll
  for (int o = 32; o; o >>= 1) s += __shfl_down(s, o);
  if (lane == 0) red[wid] = s;
  __syncthreads();
  if (tid == 0) {
    float S = red[0] + red[1] + red[2] + red[3];
    stats[0] = M;
    stats[1] = 1.0f / S;
  }
}

// ---------------------------------------------------------------------------
// K4: weighted-sum partials. grid 1024 = 128 tc x 8 strips, block 256.
// ---------------------------------------------------------------------------
__global__ __launch_bounds__(256) void k_wsum(
    const float* __restrict__ x, const float* __restrict__ logits,
    const float* __restrict__ stats, float* __restrict__ partial) {
  const int tid = threadIdx.x;
  const int lane = tid & 63, wv = tid >> 6;
  const int tc = blockIdx.x >> 3, strip = blockIdx.x & 7;
  const float M = stats[0], invS = stats[1];
  const float4* x4 = (const float4*)x;
  const int col = strip * 64 + lane;
  const int t0 = tc * 64 + wv * 16;

  float4 acc = make_float4(0.f, 0.f, 0.f, 0.f);
  #pragma unroll 4
  for (int tt = 0; tt < 16; ++tt) {
    int t = t0 + tt;
    float a = __expf(logits[t] - M) * invS;
    float4 xv = x4[t * 512 + col];
    acc.x += a * xv.x; acc.y += a * xv.y; acc.z += a * xv.z; acc.w += a * xv.w;
  }

  __shared__ float4 redx[4][64];
  redx[wv][lane] = acc;
  __syncthreads();
  if (wv == 0) {
    float4 s = redx[0][lane];
    #pragma unroll
    for (int w = 1; w < 4; ++w) {
      float4 v = redx[w][lane];
      s.x += v.x; s.y += v.y; s.z += v.z; s.w += v.w;
    }
    ((float4*)partial)[tc * 512 + col] = s;
  }
}

// ---------------------------------------------------------------------------
// K5: out[d] = sum_{tc<128} partial[tc][d]. grid 8, block 256.
// ---------------------------------------------------------------------------
__global__ __launch_bounds__(256) void k_reduce(
    const float* __restrict__ partial, float* __restrict__ out) {
  const int col = blockIdx.x * 256 + threadIdx.x;
  float s = 0.f;
  #pragma unroll 8
  for (int tc = 0; tc < 128; ++tc) s += partial[tc * 2048 + col];
  out[col] = s;
}

// ---------------------------------------------------------------------------
extern "C" void kernel_launch(void* const* d_in, const int* in_sizes, int n_in,
                              void* d_out, int out_size, void* d_ws, size_t ws_size,
                              hipStream_t stream) {
  const float* x  = (const float*)d_in[0];
  const float* w1 = (const float*)d_in[1];
  const float* b1 = (const float*)d_in[2];
  const float* w2 = (const float*)d_in[3];
  const float* b2 = (const float*)d_in[4];
  const float* w3 = (const float*)d_in[5];
  const float* b3 = (const float*)d_in[6];
  const float* w4 = (const float*)d_in[7];
  const float* b4 = (const float*)d_in[8];
  const float* w5 = (const float*)d_in[9];
  const float* b5 = (const float*)d_in[10];
  const float* Wl = (const float*)d_in[11];
  const float* bl = (const float*)d_in[12];
  float* out = (float*)d_out;

  float* ws      = (float*)d_ws;
  float* out1p   = ws;                        // 32*16*8192 = 4194304
  float* y5      = out1p + 32 * 16 * SEQ;     // 8192
  float* logits  = y5 + SEQ;                  // 8192
  float* stats   = logits + SEQ;              // 16
  float* partial = stats + 16;                // 128*2048

  k_conv1 <<<512, 256, 0, stream>>>(x, w1, out1p);
  k_chain <<<128, 128, 0, stream>>>(out1p, b1, w2, b2, w3, b3, w4, b4, w5, b5, y5);
  k_matvec<<<1024, 256, 0, stream>>>(Wl, bl, y5, logits);
  k_stats <<<1, 256, 0, stream>>>(logits, stats);
  k_wsum  <<<1024, 256, 0, stream>>>(x, logits, stats, partial);
  k_reduce<<<8, 256, 0, stream>>>(partial, out);
}

// Round 5
// 105.917 us; speedup vs baseline: 1.3243x; 1.2903x over previous
//
#include <hip/hip_runtime.h>

#define SEQ 8192
#define DIM 2048
#define NEG 0.02f

typedef short bf16x8 __attribute__((ext_vector_type(8)));
typedef float f32x4 __attribute__((ext_vector_type(4)));

// round-to-nearest-even fp32 -> bf16 (returns bits, and the bf16 value as f32)
__device__ __forceinline__ unsigned short bf16_rne(float f, float* as_f32) {
  unsigned u = __float_as_uint(f);
  unsigned r = (u + 0x7FFFu + ((u >> 16) & 1u)) >> 16;
  *as_f32 = __uint_as_float(r << 16);
  return (unsigned short)r;
}

// ---------------------------------------------------------------------------
// K0: pack w1 [16][2048][3] into MFMA A-fragment order, hi/lo bf16 planes.
// entry e = ((((sl*4+ch)*3+ko)*4+ks)*2+p)*64+lane holds 8 bf16 (j=0..7):
//   c = lane&15, kk = (lane>>4)*8+j, cin = sl*512+ch*128+ks*32+kk
// 24576 entries -> 96 blocks x 256 threads, one entry each.
// ---------------------------------------------------------------------------
__global__ __launch_bounds__(256) void k_prep_wA(
    const float* __restrict__ w1, unsigned short* __restrict__ wA) {
  int e = blockIdx.x * 256 + threadIdx.x;
  int lane = e & 63;
  int g = e >> 6;
  int p = g & 1; g >>= 1;
  int ks = g & 3; g >>= 2;
  int ko = g % 3; g /= 3;
  int ch = g & 3;
  int sl = g >> 2;
  int c = lane & 15;
  unsigned short* dst = wA + (size_t)e * 8;
  #pragma unroll
  for (int j = 0; j < 8; ++j) {
    int kk = ((lane >> 4) << 3) + j;
    int cin = sl * 512 + ch * 128 + ks * 32 + kk;
    float w = w1[c * 6144 + cin * 3 + ko];
    float hf;
    unsigned short hb = bf16_rne(w, &hf);
    if (p == 0) dst[j] = hb;
    else {
      float lf;
      dst[j] = bf16_rne(w - hf, &lf);
    }
  }
}

// ---------------------------------------------------------------------------
// K1: conv1 partials via MFMA 16x16x32 bf16 (hi/lo split = 3 passes).
// grid 512 = 128 t-blocks x 4 cin-slices, block 256 (4 waves).
// Block covers t0..t0+63 (wave wv: 16 t), cin slice of 512 (4 chunks of 128).
// LDS: x tile rows 0..65 (gt = t0-1+r) x 128 cin, bf16 hi+lo planes,
// row stride 256B, XOR-swizzle ^((r&7)<<4) -> conflict-free ds_read_b128.
// ---------------------------------------------------------------------------
__global__ __launch_bounds__(256, 2) void k_conv1(
    const float* __restrict__ x, const unsigned short* __restrict__ wA,
    float* __restrict__ out1p) {
  __shared__ char xsh[66 * 256];   // hi plane: 16.5KB
  __shared__ char xsl[66 * 256];   // lo plane

  const int tid = threadIdx.x;
  const int tb = blockIdx.x & 127;
  const int sl = blockIdx.x >> 7;         // cin slice 0..3
  const int t0 = tb << 6;
  const int lane = tid & 63;
  const int wv = tid >> 6;
  const float4* x4 = (const float4*)x;

  const int xcol = sl * 128 + (tid & 31); // float4 col within x row
  const int cq8 = (tid & 31) * 8;         // byte off of this thread's 4 cin
  const int r0s = tid >> 5;               // staging row 0..7

  f32x4 acc = {0.f, 0.f, 0.f, 0.f};

  for (int ch = 0; ch < 4; ++ch) {
    __syncthreads();
    #pragma unroll
    for (int pp = 0; pp < 9; ++pp) {
      int r = r0s + pp * 8;
      if (r < 66) {
        int gt = t0 - 1 + r;
        float4 v = make_float4(0.f, 0.f, 0.f, 0.f);
        if (gt >= 0 && gt < SEQ) v = x4[gt * 512 + ch * 32 + xcol];
        float h0f, h1f, h2f, h3f, d;
        ushort4 hv, lv;
        hv.x = bf16_rne(v.x, &h0f); lv.x = bf16_rne(v.x - h0f, &d);
        hv.y = bf16_rne(v.y, &h1f); lv.y = bf16_rne(v.y - h1f, &d);
        hv.z = bf16_rne(v.z, &h2f); lv.z = bf16_rne(v.z - h2f, &d);
        hv.w = bf16_rne(v.w, &h3f); lv.w = bf16_rne(v.w - h3f, &d);
        int off = r * 256 + (cq8 ^ ((r & 7) << 4));
        *(ushort4*)(xsh + off) = hv;
        *(ushort4*)(xsl + off) = lv;
      }
    }
    __syncthreads();

    #pragma unroll
    for (int ko = 0; ko < 3; ++ko) {
      const int lr = (wv << 4) + (lane & 15) + ko;
      const int rowb = lr * 256;
      const int sw = (lr & 7) << 4;
      #pragma unroll
      for (int ks = 0; ks < 4; ++ks) {
        int ebase = (((((sl * 4 + ch) * 3 + ko) * 4 + ks) * 2) << 6) + lane;
        bf16x8 Ah = *(const bf16x8*)(wA + (size_t)ebase * 8);
        bf16x8 Al = *(const bf16x8*)(wA + (size_t)(ebase + 64) * 8);
        int cb = ((ks << 6) + ((lane >> 4) << 4)) ^ sw;
        bf16x8 Bh = *(const bf16x8*)(xsh + rowb + cb);
        bf16x8 Bl = *(const bf16x8*)(xsl + rowb + cb);
        acc = __builtin_amdgcn_mfma_f32_16x16x32_bf16(Ah, Bh, acc, 0, 0, 0);
        acc = __builtin_amdgcn_mfma_f32_16x16x32_bf16(Ah, Bl, acc, 0, 0, 0);
        acc = __builtin_amdgcn_mfma_f32_16x16x32_bf16(Al, Bh, acc, 0, 0, 0);
      }
    }
  }

  const int t = t0 + (wv << 4) + (lane & 15);
  const int c0 = (lane >> 4) << 2;
  #pragma unroll
  for (int i = 0; i < 4; ++i)
    out1p[(sl * 16 + c0 + i) * SEQ + t] = acc[i];
}

// ---------------------------------------------------------------------------
// K2: sum 4 conv1 partials + bias + leaky, then conv2..conv5 fused.
// grid 128, block 128, T=64 per block. j in 0..71 <-> t = t0-4+j.
// ---------------------------------------------------------------------------
__global__ __launch_bounds__(128) void k_chain(
    const float* __restrict__ out1p, const float* __restrict__ b1,
    const float* __restrict__ w2, const float* __restrict__ b2,
    const float* __restrict__ w3, const float* __restrict__ b3,
    const float* __restrict__ w4, const float* __restrict__ b4,
    const float* __restrict__ w5, const float* __restrict__ b5,
    float* __restrict__ y5) {
  __shared__ float l1[16][72], l2[8][72], l3[4][72], l4[2][72];
  __shared__ float w2s[384], w3s[96], w4s[24], w5s[6];
  __shared__ float bs[16];

  const int tid = threadIdx.x;
  const int t0 = blockIdx.x * 64;

  for (int i = tid; i < 384; i += 128) w2s[i] = w2[i];
  if (tid < 96) w3s[tid] = w3[tid];
  else if (tid < 120) w4s[tid - 96] = w4[tid - 96];
  else if (tid == 120) { for (int i = 0; i < 6; ++i) w5s[i] = w5[i]; }
  else if (tid == 121) {
    for (int i = 0; i < 8; ++i) bs[i] = b2[i];
    for (int i = 0; i < 4; ++i) bs[8 + i] = b3[i];
    bs[12] = b4[0]; bs[13] = b4[1]; bs[14] = b5[0];
  }

  const float4* p4 = (const float4*)out1p;
  for (int idx = tid; idx < 16 * 18; idx += 128) {
    int cc = idx / 18, m = idx - cc * 18;
    int gt0 = t0 - 4 + 4 * m;
    if (gt0 >= 0 && gt0 < SEQ) {
      float4 a = make_float4(0.f, 0.f, 0.f, 0.f);
      int base = cc * 2048 + (gt0 >> 2);
      #pragma unroll
      for (int s = 0; s < 4; ++s) {
        float4 v = p4[s * 16 * 2048 + base];
        a.x += v.x; a.y += v.y; a.z += v.z; a.w += v.w;
      }
      float bb = b1[cc];
      float e0 = a.x + bb, e1 = a.y + bb, e2 = a.z + bb, e3 = a.w + bb;
      l1[cc][4 * m + 0] = (e0 >= 0.f) ? e0 : NEG * e0;
      l1[cc][4 * m + 1] = (e1 >= 0.f) ? e1 : NEG * e1;
      l1[cc][4 * m + 2] = (e2 >= 0.f) ? e2 : NEG * e2;
      l1[cc][4 * m + 3] = (e3 >= 0.f) ? e3 : NEG * e3;
    } else {
      l1[cc][4 * m + 0] = 0.f; l1[cc][4 * m + 1] = 0.f;
      l1[cc][4 * m + 2] = 0.f; l1[cc][4 * m + 3] = 0.f;
    }
  }
  __syncthreads();

  for (int o = tid; o < 560; o += 128) {
    int j = (o >> 3) + 1, cc = o & 7;
    float acc = bs[cc];
    #pragma unroll
    for (int ci = 0; ci < 16; ++ci) {
      acc += w2s[cc * 48 + ci * 3 + 0] * l1[ci][j - 1];
      acc += w2s[cc * 48 + ci * 3 + 1] * l1[ci][j];
      acc += w2s[cc * 48 + ci * 3 + 2] * l1[ci][j + 1];
    }
    l2[cc][j] = (acc >= 0.f) ? acc : NEG * acc;
  }
  __syncthreads();

  for (int o = tid; o < 272; o += 128) {
    int j = (o >> 2) + 2, cc = o & 3;
    float acc = bs[8 + cc];
    #pragma unroll
    for (int ci = 0; ci < 8; ++ci) {
      acc += w3s[cc * 24 + ci * 3 + 0] * l2[ci][j - 1];
      acc += w3s[cc * 24 + ci * 3 + 1] * l2[ci][j];
      acc += w3s[cc * 24 + ci * 3 + 2] * l2[ci][j + 1];
    }
    l3[cc][j] = (acc >= 0.f) ? acc : NEG * acc;
  }
  __syncthreads();

  for (int o = tid; o < 132; o += 128) {
    int j = (o >> 1) + 3, cc = o & 1;
    float acc = bs[12 + cc];
    #pragma unroll
    for (int ci = 0; ci < 4; ++ci) {
      acc += w4s[cc * 12 + ci * 3 + 0] * l3[ci][j - 1];
      acc += w4s[cc * 12 + ci * 3 + 1] * l3[ci][j];
      acc += w4s[cc * 12 + ci * 3 + 2] * l3[ci][j + 1];
    }
    l4[cc][j] = (acc >= 0.f) ? acc : NEG * acc;
  }
  __syncthreads();

  for (int o = tid; o < 64; o += 128) {
    int j = o + 4;
    float acc = bs[14];
    #pragma unroll
    for (int ci = 0; ci < 2; ++ci) {
      acc += w5s[ci * 3 + 0] * l4[ci][j - 1];
      acc += w5s[ci * 3 + 1] * l4[ci][j];
      acc += w5s[ci * 3 + 2] * l4[ci][j + 1];
    }
    y5[t0 + o] = (acc >= 0.f) ? acc : NEG * acc;
  }
}

// ---------------------------------------------------------------------------
// K3: logits = Wl @ y5 + bl. grid 1024 (8 rows/block), block 256.
// ---------------------------------------------------------------------------
__global__ __launch_bounds__(256) void k_matvec(
    const float* __restrict__ Wl, const float* __restrict__ bl,
    const float* __restrict__ y5, float* __restrict__ logits) {
  const int tid = threadIdx.x;
  const int r0 = blockIdx.x * 8;
  const float4* W4 = (const float4*)Wl;
  const float4* y4 = (const float4*)y5;

  float a[8];
  #pragma unroll
  for (int r = 0; r < 8; ++r) a[r] = 0.f;

  #pragma unroll 2
  for (int u = 0; u < 8; ++u) {
    int i = u * 256 + tid;
    float4 yv = y4[i];
    #pragma unroll
    for (int r = 0; r < 8; ++r) {
      float4 wv = W4[(r0 + r) * 2048 + i];
      a[r] += wv.x * yv.x + wv.y * yv.y + wv.z * yv.z + wv.w * yv.w;
    }
  }
  #pragma unroll
  for (int o = 32; o; o >>= 1) {
    #pragma unroll
    for (int r = 0; r < 8; ++r) a[r] += __shfl_down(a[r], o);
  }
  __shared__ float red[4][8];
  const int lane = tid & 63, wid = tid >> 6;
  if (lane == 0) {
    #pragma unroll
    for (int r = 0; r < 8; ++r) red[wid][r] = a[r];
  }
  __syncthreads();
  if (tid < 8) {
    float s = red[0][tid] + red[1][tid] + red[2][tid] + red[3][tid];
    logits[r0 + tid] = s + bl[r0 + tid];
  }
}

// ---------------------------------------------------------------------------
// K3.5: softmax stats -> stats[0]=M, stats[1]=1/S. grid 1.
// ---------------------------------------------------------------------------
__global__ __launch_bounds__(256) void k_stats(
    const float* __restrict__ logits, float* __restrict__ stats) {
  __shared__ float red[4];
  const int tid = threadIdx.x;
  const int lane = tid & 63, wid = tid >> 6;

  float lv[32];
  #pragma unroll
  for (int i = 0; i < 32; ++i) lv[i] = logits[tid + 256 * i];

  float m = lv[0];
  #pragma unroll
  for (int i = 1; i < 32; ++i) m = fmaxf(m, lv[i]);
  #pragma unroll
  for (int o = 32; o; o >>= 1) m = fmaxf(m, __shfl_down(m, o));
  if (lane == 0) red[wid] = m;
  __syncthreads();
  const float M = fmaxf(fmaxf(red[0], red[1]), fmaxf(red[2], red[3]));
  __syncthreads();

  float s = 0.f;
  #pragma unroll
  for (int i = 0; i < 32; ++i) s += __expf(lv[i] - M);
  #pragma unroll
  for (int o = 32; o; o >>= 1) s += __shfl_down(s, o);
  if (lane == 0) red[wid] = s;
  __syncthreads();
  if (tid == 0) {
    float S = red[0] + red[1] + red[2] + red[3];
    stats[0] = M;
    stats[1] = 1.0f / S;
  }
}

// ---------------------------------------------------------------------------
// K4: weighted-sum partials. grid 1024 = 128 tc x 8 strips, block 256.
// ---------------------------------------------------------------------------
__global__ __launch_bounds__(256) void k_wsum(
    const float* __restrict__ x, const float* __restrict__ logits,
    const float* __restrict__ stats, float* __restrict__ partial) {
  const int tid = threadIdx.x;
  const int lane = tid & 63, wv = tid >> 6;
  const int tc = blockIdx.x >> 3, strip = blockIdx.x & 7;
  const float M = stats[0], invS = stats[1];
  const float4* x4 = (const float4*)x;
  const int col = strip * 64 + lane;
  const int t0 = tc * 64 + wv * 16;

  float4 acc = make_float4(0.f, 0.f, 0.f, 0.f);
  #pragma unroll 4
  for (int tt = 0; tt < 16; ++tt) {
    int t = t0 + tt;
    float a = __expf(logits[t] - M) * invS;
    float4 xv = x4[t * 512 + col];
    acc.x += a * xv.x; acc.y += a * xv.y; acc.z += a * xv.z; acc.w += a * xv.w;
  }

  __shared__ float4 redx[4][64];
  redx[wv][lane] = acc;
  __syncthreads();
  if (wv == 0) {
    float4 s = redx[0][lane];
    #pragma unroll
    for (int w = 1; w < 4; ++w) {
      float4 v = redx[w][lane];
      s.x += v.x; s.y += v.y; s.z += v.z; s.w += v.w;
    }
    ((float4*)partial)[tc * 512 + col] = s;
  }
}

// ---------------------------------------------------------------------------
// K5: out[d] = sum_{tc<128} partial[tc][d]. grid 8, block 256.
// ---------------------------------------------------------------------------
__global__ __launch_bounds__(256) void k_reduce(
    const float* __restrict__ partial, float* __restrict__ out) {
  const int col = blockIdx.x * 256 + threadIdx.x;
  float s = 0.f;
  #pragma unroll 8
  for (int tc = 0; tc < 128; ++tc) s += partial[tc * 2048 + col];
  out[col] = s;
}

// ---------------------------------------------------------------------------
extern "C" void kernel_launch(void* const* d_in, const int* in_sizes, int n_in,
                              void* d_out, int out_size, void* d_ws, size_t ws_size,
                              hipStream_t stream) {
  const float* x  = (const float*)d_in[0];
  const float* w1 = (const float*)d_in[1];
  const float* b1 = (const float*)d_in[2];
  const float* w2 = (const float*)d_in[3];
  const float* b2 = (const float*)d_in[4];
  const float* w3 = (const float*)d_in[5];
  const float* b3 = (const float*)d_in[6];
  const float* w4 = (const float*)d_in[7];
  const float* b4 = (const float*)d_in[8];
  const float* w5 = (const float*)d_in[9];
  const float* b5 = (const float*)d_in[10];
  const float* Wl = (const float*)d_in[11];
  const float* bl = (const float*)d_in[12];
  float* out = (float*)d_out;

  float* ws      = (float*)d_ws;
  unsigned short* wA = (unsigned short*)ws;   // 196608 ushort = 98304 f
  float* out1p   = ws + 98304;                // 4*16*8192 = 524288
  float* y5      = out1p + 4 * 16 * SEQ;      // 8192
  float* logits  = y5 + SEQ;                  // 8192
  float* stats   = logits + SEQ;              // 16
  float* partial = stats + 16;                // 128*2048

  k_prep_wA<<<96, 256, 0, stream>>>(w1, wA);
  k_conv1  <<<512, 256, 0, stream>>>(x, wA, out1p);
  k_chain  <<<128, 128, 0, stream>>>(out1p, b1, w2, b2, w3, b3, w4, b4, w5, b5, y5);
  k_matvec <<<1024, 256, 0, stream>>>(Wl, bl, y5, logits);
  k_stats  <<<1, 256, 0, stream>>>(logits, stats);
  k_wsum   <<<1024, 256, 0, stream>>>(x, logits, stats, partial);
  k_reduce <<<8, 256, 0, stream>>>(partial, out);
}